// Round 8
// baseline (139.371 us; speedup 1.0000x reference)
//
#include <hip/hip_runtime.h>
#include <hip/hip_bf16.h>

#define N_NODES 4096
#define IN_F    512
#define HEADS   8
#define DH      64
#define HD      512   // HEADS*DH
#define MAXNBR  512

typedef __bf16 bf16x8 __attribute__((ext_vector_type(8)));
typedef float  f32x4  __attribute__((ext_vector_type(4)));

__device__ __forceinline__ float bf_lo(unsigned u) { return __uint_as_float(u << 16); }
__device__ __forceinline__ float bf_hi(unsigned u) { return __uint_as_float(u & 0xffff0000u); }

// ---------------- Kernel A: 1536 blocks.
//  b%3==0 (512 blocks): GEMM mx = bf16(X) @ bf16(W)^T + fused et epilogue (identical to R7 k1).
//  else  (1024 blocks): adj scan -> compacted neighbor lists nbr[i][.] + cnt[i] (4 rows/block).
// Roles interleaved by blockIdx so both populations co-reside on every CU:
// the scan's 64 MB HBM stream overlaps the GEMM's MFMA/LDS work (disjoint pipes).
#define KP 72   // 144 B LDS rows: 16B-aligned for ds_*_b128

__global__ __launch_bounds__(256, 2) void kA(const float* __restrict__ X,
                                             const float* __restrict__ W,
                                             const float* __restrict__ adj,
                                             const float* __restrict__ a_dst,
                                             __bf16* __restrict__ mx,
                                             float* __restrict__ et,
                                             int* __restrict__ nbr,
                                             int* __restrict__ cnt) {
    __shared__ __attribute__((aligned(16))) char smem[37504];
    int b = blockIdx.x, tid = threadIdx.x;

    if (b % 3 == 0) {
        // ======== GEMM block (identical math to R7 k1_gemm) ========
        __bf16* As = (__bf16*)smem;             // [2][64][KP]
        __bf16* Bs = (__bf16*)(smem + 18432);   // [2][64][KP]
        float*  ts = (float*)(smem + 36864);    // [2][64]
        int gid  = b / 3;
        int h    = gid & 7;
        int y    = gid >> 3;
        int row0 = y * 64, col0 = h * 64;
        int wave = tid >> 6, lane = tid & 63;
        int wm = wave >> 1, wn = wave & 1;
        int lr = lane & 15, kg = lane >> 4;

        f32x4 acc[2][2] = {};

        int sr = tid >> 3, sc = (tid & 7) * 8;
        const float* aptr0 = X + (size_t)(row0 + sr) * IN_F + sc;
        const float* aptr1 = aptr0 + (size_t)32 * IN_F;
        int dcol = tid & 63, fq = (tid >> 6) * 16;
        const float* wptr = W + ((size_t)h * IN_F + fq) * DH + dcol;

        f32x4 pa00 = *(const f32x4*)aptr0, pa01 = *(const f32x4*)(aptr0 + 4);
        f32x4 pa10 = *(const f32x4*)aptr1, pa11 = *(const f32x4*)(aptr1 + 4);
        float wv[16];
        #pragma unroll
        for (int i = 0; i < 16; ++i) wv[i] = wptr[(size_t)i * DH];

        float ad0 = a_dst[h * DH + wn * 32 + lr];
        float ad1 = a_dst[h * DH + wn * 32 + 16 + lr];

        #pragma unroll
        for (int k = 0; k < IN_F / 64; ++k) {
            int cur = k & 1;
            bf16x8 a0 = { (__bf16)pa00[0], (__bf16)pa00[1], (__bf16)pa00[2], (__bf16)pa00[3],
                          (__bf16)pa01[0], (__bf16)pa01[1], (__bf16)pa01[2], (__bf16)pa01[3] };
            bf16x8 a1 = { (__bf16)pa10[0], (__bf16)pa10[1], (__bf16)pa10[2], (__bf16)pa10[3],
                          (__bf16)pa11[0], (__bf16)pa11[1], (__bf16)pa11[2], (__bf16)pa11[3] };
            bf16x8 b0 = { (__bf16)wv[0],  (__bf16)wv[1],  (__bf16)wv[2],  (__bf16)wv[3],
                          (__bf16)wv[4],  (__bf16)wv[5],  (__bf16)wv[6],  (__bf16)wv[7] };
            bf16x8 b1 = { (__bf16)wv[8],  (__bf16)wv[9],  (__bf16)wv[10], (__bf16)wv[11],
                          (__bf16)wv[12], (__bf16)wv[13], (__bf16)wv[14], (__bf16)wv[15] };
            *(bf16x8*)&As[(cur * 64 + sr) * KP + sc]       = a0;
            *(bf16x8*)&As[(cur * 64 + sr + 32) * KP + sc]  = a1;
            *(bf16x8*)&Bs[(cur * 64 + dcol) * KP + fq]     = b0;   // transpose here
            *(bf16x8*)&Bs[(cur * 64 + dcol) * KP + fq + 8] = b1;
            if (k + 1 < IN_F / 64) {
                int off = (k + 1) * 64;
                pa00 = *(const f32x4*)(aptr0 + off); pa01 = *(const f32x4*)(aptr0 + off + 4);
                pa10 = *(const f32x4*)(aptr1 + off); pa11 = *(const f32x4*)(aptr1 + off + 4);
                const float* wp = wptr + (size_t)off * DH;
                #pragma unroll
                for (int i = 0; i < 16; ++i) wv[i] = wp[(size_t)i * DH];
            }
            __syncthreads();
            #pragma unroll
            for (int kc = 0; kc < 2; ++kc) {
                bf16x8 af0 = *(const bf16x8*)&As[(cur * 64 + wm * 32 + lr) * KP      + kc * 32 + kg * 8];
                bf16x8 af1 = *(const bf16x8*)&As[(cur * 64 + wm * 32 + 16 + lr) * KP + kc * 32 + kg * 8];
                bf16x8 bf0 = *(const bf16x8*)&Bs[(cur * 64 + wn * 32 + lr) * KP      + kc * 32 + kg * 8];
                bf16x8 bf1 = *(const bf16x8*)&Bs[(cur * 64 + wn * 32 + 16 + lr) * KP + kc * 32 + kg * 8];
                acc[0][0] = __builtin_amdgcn_mfma_f32_16x16x32_bf16(af0, bf0, acc[0][0], 0, 0, 0);
                acc[0][1] = __builtin_amdgcn_mfma_f32_16x16x32_bf16(af0, bf1, acc[0][1], 0, 0, 0);
                acc[1][0] = __builtin_amdgcn_mfma_f32_16x16x32_bf16(af1, bf0, acc[1][0], 0, 0, 0);
                acc[1][1] = __builtin_amdgcn_mfma_f32_16x16x32_bf16(af1, bf1, acc[1][1], 0, 0, 0);
            }
            // single barrier/iter: buffer written at k+1 was last read at k-1 (barrier k between)
        }

        // epilogue 1: mx store.  C/D layout: col=lane&15, row=(lane>>4)*4+reg
        #pragma unroll
        for (int mt = 0; mt < 2; ++mt) {
            #pragma unroll
            for (int nt = 0; nt < 2; ++nt) {
                int col = col0 + wn * 32 + nt * 16 + lr;
                #pragma unroll
                for (int r = 0; r < 4; ++r) {
                    int row = row0 + wm * 32 + mt * 16 + kg * 4 + r;
                    mx[(size_t)row * HD + col] = (__bf16)acc[mt][nt][r];
                }
            }
        }
        // epilogue 2: et[row][h] = exp(sum_d acc*a_dst) from pre-rounding fp32 acc
        #pragma unroll
        for (int mt = 0; mt < 2; ++mt) {
            #pragma unroll
            for (int r = 0; r < 4; ++r) {
                float p = ad0 * acc[mt][0][r] + ad1 * acc[mt][1][r];
                p += __shfl_xor(p, 1);
                p += __shfl_xor(p, 2);
                p += __shfl_xor(p, 4);
                p += __shfl_xor(p, 8);
                if (lr == 0) ts[wn * 64 + wm * 32 + mt * 16 + kg * 4 + r] = p;
            }
        }
        __syncthreads();
        if (tid < 64) {
            float t = ts[tid] + ts[64 + tid];
            et[(size_t)(row0 + tid) * HEADS + h] = __expf(t);
        }
    } else {
        // ======== scan block: 4 adj rows -> compacted nbr lists ========
        int sid = b - b / 3 - 1;          // 0..1023
        int* jl = (int*)smem;             // 512 ints
        int* cp = (int*)(smem + 4096);
        int j0 = tid * 16;
        for (int r = 0; r < 4; ++r) {
            int i = sid * 4 + r;
            if (tid == 0) *cp = 0;
            __syncthreads();
            const float* arow = adj + (size_t)i * N_NODES + j0;
            #pragma unroll
            for (int q = 0; q < 4; ++q) {
                uint4 p = *(const uint4*)(arow + q * 4);
                int jb = j0 + q * 4;
                if (p.x) { int s = atomicAdd(cp, 1); if (s < MAXNBR) jl[s] = jb;     }
                if (p.y) { int s = atomicAdd(cp, 1); if (s < MAXNBR) jl[s] = jb + 1; }
                if (p.z) { int s = atomicAdd(cp, 1); if (s < MAXNBR) jl[s] = jb + 2; }
                if (p.w) { int s = atomicAdd(cp, 1); if (s < MAXNBR) jl[s] = jb + 3; }
            }
            __syncthreads();
            int c = *cp; if (c > MAXNBR) c = MAXNBR;
            for (int s = tid; s < c; s += 256) nbr[(size_t)i * MAXNBR + s] = jl[s];
            if (tid == 0) cnt[i] = c;
            __syncthreads();   // protect jl/cp before next row reuses them
        }
    }
}

// ---------------- Kernel B: per row i — aggregation from compacted neighbor lists
__global__ __launch_bounds__(256) void k3b(const int* __restrict__ nbr,
                                           const int* __restrict__ cnt,
                                           const __bf16* __restrict__ mx,
                                           const float* __restrict__ et,
                                           float* __restrict__ out) {
    __shared__ int   jlist[MAXNBR];
    __shared__ float el[MAXNBR * 8];
    int tid = threadIdx.x;
    int i   = blockIdx.x;
    int c   = cnt[i];

    for (int s = tid; s < c; s += 256) jlist[s] = nbr[(size_t)i * MAXNBR + s];
    __syncthreads();
    for (int idx = tid; idx < c * 8; idx += 256)
        el[idx] = et[(size_t)jlist[idx >> 3] * 8 + (idx & 7)];
    __syncthreads();

    // phase B: thread owns 2 adjacent cols (2tid, 2tid+1), head h = tid>>5; one 4B load/j.
    int h = tid >> 5;
    const unsigned* mxu = (const unsigned*)mx;   // 256 uints per row
    float a0 = 0.f, a1 = 0.f, d = 0.f;
    int k = 0;
    for (; k + 4 <= c; k += 4) {
        int j0_ = jlist[k], j1_ = jlist[k+1], j2_ = jlist[k+2], j3_ = jlist[k+3];
        float e0 = el[(k    ) * 8 + h], e1 = el[(k + 1) * 8 + h];
        float e2 = el[(k + 2) * 8 + h], e3 = el[(k + 3) * 8 + h];
        unsigned p0 = mxu[(size_t)j0_ * 256 + tid];
        unsigned p1 = mxu[(size_t)j1_ * 256 + tid];
        unsigned p2 = mxu[(size_t)j2_ * 256 + tid];
        unsigned p3 = mxu[(size_t)j3_ * 256 + tid];
        a0 += e0 * bf_lo(p0) + e1 * bf_lo(p1) + e2 * bf_lo(p2) + e3 * bf_lo(p3);
        a1 += e0 * bf_hi(p0) + e1 * bf_hi(p1) + e2 * bf_hi(p2) + e3 * bf_hi(p3);
        d  += e0 + e1 + e2 + e3;
    }
    for (; k < c; ++k) {
        int j = jlist[k];
        float e = el[k * 8 + h];
        unsigned p = mxu[(size_t)j * 256 + tid];
        a0 += e * bf_lo(p);
        a1 += e * bf_hi(p);
        d  += e;
    }
    float inv = 1.f / d;
    out[(size_t)i * HD + tid * 2]     = a0 * inv;
    out[(size_t)i * HD + tid * 2 + 1] = a1 * inv;
}

extern "C" void kernel_launch(void* const* d_in, const int* in_sizes, int n_in,
                              void* d_out, int out_size, void* d_ws, size_t ws_size,
                              hipStream_t stream) {
    const float* x     = (const float*)d_in[0];
    const float* adj   = (const float*)d_in[1];
    const float* W     = (const float*)d_in[2];
    // d_in[3] = a_origin: dead (softmax shift invariance over j)
    const float* a_dst = (const float*)d_in[4];
    float* out = (float*)d_out;

    char* ws = (char*)d_ws;
    __bf16* mx  = (__bf16*)ws;                    // 4 MB    [4096][512]
    float*  et  = (float*)(ws + 4194304);         // 128 KB  [4096][8]
    int*    nbr = (int*)(ws + 4325376);           // 8 MB    [4096][512]
    int*    cnt = (int*)(ws + 12713984);          // 16 KB   [4096]

    kA <<<dim3(1536), dim3(256), 0, stream>>>(x, W, adj, a_dst, mx, et, nbr, cnt);
    k3b<<<dim3(N_NODES), dim3(256), 0, stream>>>(nbr, cnt, mx, et, out);
}

// Round 9
// 132.688 us; speedup vs baseline: 1.0504x; 1.0504x over previous
//
#include <hip/hip_runtime.h>
#include <hip/hip_bf16.h>

#define N_NODES 4096
#define IN_F    512
#define HEADS   8
#define DH      64
#define HD      512   // HEADS*DH

typedef __bf16 bf16x8 __attribute__((ext_vector_type(8)));
typedef float  f32x4  __attribute__((ext_vector_type(4)));

__device__ __forceinline__ float bf_lo(unsigned u) { return __uint_as_float(u << 16); }
__device__ __forceinline__ float bf_hi(unsigned u) { return __uint_as_float(u & 0xffff0000u); }

// ---------------- Kernel 1: GEMM  mx[n][h*64+d] = sum_f X[n][f] * W[h][f][d]
// Self-contained: A (X fp32) cvt->bf16 inline; B (W fp32) transposed in-staging
// (W[h] = 128 KB, XCD-L2-resident since h = blockIdx.x&7 pins heads to XCDs).
// + fused et epilogue: et[n][h] = exp( sum_d acc_fp32[n][d] * a_dst[h][d] ).
// BM=BN=BK=64, 512 blocks (2/CU), register-prefetch + dbuf LDS, 1 barrier/iter.
#define KP 72   // 144 B rows: 16B-aligned for ds_*_b128

__global__ __launch_bounds__(256, 2) void k1_gemm(const float* __restrict__ X,
                                                  const float* __restrict__ W,
                                                  const float* __restrict__ a_dst,
                                                  __bf16* __restrict__ C,
                                                  float* __restrict__ et) {
    __shared__ __bf16 As[2][64][KP];
    __shared__ __bf16 Bs[2][64][KP];
    __shared__ float  ts[2][64];
    int tid  = threadIdx.x;
    int h    = blockIdx.x & 7;     // head round-robins the 8 XCDs
    int y    = blockIdx.x >> 3;
    int row0 = y * 64, col0 = h * 64;
    int wave = tid >> 6, lane = tid & 63;
    int wm = wave >> 1, wn = wave & 1;
    int lr = lane & 15, kg = lane >> 4;

    f32x4 acc[2][2] = {};

    // A staging: thread -> rows (sr, sr+32), 8 cols at sc
    int sr = tid >> 3, sc = (tid & 7) * 8;
    const float* aptr0 = X + (size_t)(row0 + sr) * IN_F + sc;
    const float* aptr1 = aptr0 + (size_t)32 * IN_F;
    // B staging (transposing): thread -> col d, 16 f-rows at fq
    int dcol = tid & 63, fq = (tid >> 6) * 16;
    const float* wptr = W + ((size_t)h * IN_F + fq) * DH + dcol;

    f32x4 pa00 = *(const f32x4*)aptr0, pa01 = *(const f32x4*)(aptr0 + 4);
    f32x4 pa10 = *(const f32x4*)aptr1, pa11 = *(const f32x4*)(aptr1 + 4);
    float wv[16];
    #pragma unroll
    for (int i = 0; i < 16; ++i) wv[i] = wptr[(size_t)i * DH];

    float ad0 = a_dst[h * DH + wn * 32 + lr];
    float ad1 = a_dst[h * DH + wn * 32 + 16 + lr];

    #pragma unroll
    for (int k = 0; k < IN_F / 64; ++k) {
        int cur = k & 1;
        bf16x8 a0 = { (__bf16)pa00[0], (__bf16)pa00[1], (__bf16)pa00[2], (__bf16)pa00[3],
                      (__bf16)pa01[0], (__bf16)pa01[1], (__bf16)pa01[2], (__bf16)pa01[3] };
        bf16x8 a1 = { (__bf16)pa10[0], (__bf16)pa10[1], (__bf16)pa10[2], (__bf16)pa10[3],
                      (__bf16)pa11[0], (__bf16)pa11[1], (__bf16)pa11[2], (__bf16)pa11[3] };
        bf16x8 b0 = { (__bf16)wv[0],  (__bf16)wv[1],  (__bf16)wv[2],  (__bf16)wv[3],
                      (__bf16)wv[4],  (__bf16)wv[5],  (__bf16)wv[6],  (__bf16)wv[7] };
        bf16x8 b1 = { (__bf16)wv[8],  (__bf16)wv[9],  (__bf16)wv[10], (__bf16)wv[11],
                      (__bf16)wv[12], (__bf16)wv[13], (__bf16)wv[14], (__bf16)wv[15] };
        *(bf16x8*)&As[cur][sr][sc]        = a0;
        *(bf16x8*)&As[cur][sr + 32][sc]   = a1;
        *(bf16x8*)&Bs[cur][dcol][fq]      = b0;   // Bs[d][f] = W^T : transpose done here
        *(bf16x8*)&Bs[cur][dcol][fq + 8]  = b1;
        if (k + 1 < IN_F / 64) {
            int off = (k + 1) * 64;
            pa00 = *(const f32x4*)(aptr0 + off); pa01 = *(const f32x4*)(aptr0 + off + 4);
            pa10 = *(const f32x4*)(aptr1 + off); pa11 = *(const f32x4*)(aptr1 + off + 4);
            const float* wp = wptr + (size_t)off * DH;
            #pragma unroll
            for (int i = 0; i < 16; ++i) wv[i] = wp[(size_t)i * DH];
        }
        __syncthreads();
        #pragma unroll
        for (int kc = 0; kc < 2; ++kc) {
            bf16x8 af0 = *(const bf16x8*)&As[cur][wm * 32 + lr]     [kc * 32 + kg * 8];
            bf16x8 af1 = *(const bf16x8*)&As[cur][wm * 32 + 16 + lr][kc * 32 + kg * 8];
            bf16x8 bf0 = *(const bf16x8*)&Bs[cur][wn * 32 + lr]     [kc * 32 + kg * 8];
            bf16x8 bf1 = *(const bf16x8*)&Bs[cur][wn * 32 + 16 + lr][kc * 32 + kg * 8];
            acc[0][0] = __builtin_amdgcn_mfma_f32_16x16x32_bf16(af0, bf0, acc[0][0], 0, 0, 0);
            acc[0][1] = __builtin_amdgcn_mfma_f32_16x16x32_bf16(af0, bf1, acc[0][1], 0, 0, 0);
            acc[1][0] = __builtin_amdgcn_mfma_f32_16x16x32_bf16(af1, bf0, acc[1][0], 0, 0, 0);
            acc[1][1] = __builtin_amdgcn_mfma_f32_16x16x32_bf16(af1, bf1, acc[1][1], 0, 0, 0);
        }
        // single barrier/iter: buffer written at k+1 was last read at k-1 (barrier k between)
    }

    // epilogue 1: mx store.  C/D layout: col=lane&15, row=(lane>>4)*4+reg
    #pragma unroll
    for (int mt = 0; mt < 2; ++mt) {
        #pragma unroll
        for (int nt = 0; nt < 2; ++nt) {
            int col = col0 + wn * 32 + nt * 16 + lr;
            #pragma unroll
            for (int r = 0; r < 4; ++r) {
                int row = row0 + wm * 32 + mt * 16 + kg * 4 + r;
                C[(size_t)row * HD + col] = (__bf16)acc[mt][nt][r];
            }
        }
    }
    // epilogue 2: et[row][h] = exp(sum_d acc*a_dst) from pre-rounding fp32 acc
    #pragma unroll
    for (int mt = 0; mt < 2; ++mt) {
        #pragma unroll
        for (int r = 0; r < 4; ++r) {
            float p = ad0 * acc[mt][0][r] + ad1 * acc[mt][1][r];
            p += __shfl_xor(p, 1);
            p += __shfl_xor(p, 2);
            p += __shfl_xor(p, 4);
            p += __shfl_xor(p, 8);
            if (lr == 0) ts[wn][wm * 32 + mt * 16 + kg * 4 + r] = p;
        }
    }
    __syncthreads();
    if (tid < 64) {
        float t = ts[0][tid] + ts[1][tid];
        et[(size_t)(row0 + tid) * HEADS + h] = __expf(t);
    }
}

// ---------------- Kernel 3: per row i — neighbor scan + softmax-weighted aggregation
#define MAXNBR 512
__global__ __launch_bounds__(256) void k3_aggr(const float* __restrict__ adj,
                                               const __bf16* __restrict__ mx,
                                               const float* __restrict__ et,
                                               float* __restrict__ out) {
    __shared__ int   jlist[MAXNBR];
    __shared__ float el[MAXNBR * 8];
    __shared__ int   cnt;
    int tid = threadIdx.x;
    int i   = blockIdx.x;
    if (tid == 0) cnt = 0;
    __syncthreads();

    // phase A: scan adj row (16 KB coalesced), push nonzero j
    {
        const float* arow = adj + (size_t)i * N_NODES;
        int j0 = tid * 16;
        #pragma unroll
        for (int q = 0; q < 4; ++q) {
            uint4 p = *(const uint4*)(arow + j0 + q * 4);
            int jb = j0 + q * 4;
            if (p.x) { int s = atomicAdd(&cnt, 1); if (s < MAXNBR) jlist[s] = jb;     }
            if (p.y) { int s = atomicAdd(&cnt, 1); if (s < MAXNBR) jlist[s] = jb + 1; }
            if (p.z) { int s = atomicAdd(&cnt, 1); if (s < MAXNBR) jlist[s] = jb + 2; }
            if (p.w) { int s = atomicAdd(&cnt, 1); if (s < MAXNBR) jlist[s] = jb + 3; }
        }
    }
    __syncthreads();
    int c = cnt < MAXNBR ? cnt : MAXNBR;

    // phase A2: gather exp(t) for neighbors, all heads
    for (int idx = tid; idx < c * 8; idx += 256)
        el[idx] = et[(size_t)jlist[idx >> 3] * 8 + (idx & 7)];
    __syncthreads();

    // phase B: thread owns 2 adjacent cols (2tid, 2tid+1), head h = tid>>5; one 4B load/j.
    int h = tid >> 5;
    const unsigned* mxu = (const unsigned*)mx;   // 256 uints per row
    float a0 = 0.f, a1 = 0.f, d = 0.f;
    int k = 0;
    for (; k + 4 <= c; k += 4) {
        int j0_ = jlist[k], j1_ = jlist[k+1], j2_ = jlist[k+2], j3_ = jlist[k+3];
        float e0 = el[(k    ) * 8 + h], e1 = el[(k + 1) * 8 + h];
        float e2 = el[(k + 2) * 8 + h], e3 = el[(k + 3) * 8 + h];
        unsigned p0 = mxu[(size_t)j0_ * 256 + tid];
        unsigned p1 = mxu[(size_t)j1_ * 256 + tid];
        unsigned p2 = mxu[(size_t)j2_ * 256 + tid];
        unsigned p3 = mxu[(size_t)j3_ * 256 + tid];
        a0 += e0 * bf_lo(p0) + e1 * bf_lo(p1) + e2 * bf_lo(p2) + e3 * bf_lo(p3);
        a1 += e0 * bf_hi(p0) + e1 * bf_hi(p1) + e2 * bf_hi(p2) + e3 * bf_hi(p3);
        d  += e0 + e1 + e2 + e3;
    }
    for (; k < c; ++k) {
        int j = jlist[k];
        float e = el[k * 8 + h];
        unsigned p = mxu[(size_t)j * 256 + tid];
        a0 += e * bf_lo(p);
        a1 += e * bf_hi(p);
        d  += e;
    }
    float inv = 1.f / d;
    out[(size_t)i * HD + tid * 2]     = a0 * inv;
    out[(size_t)i * HD + tid * 2 + 1] = a1 * inv;
}

extern "C" void kernel_launch(void* const* d_in, const int* in_sizes, int n_in,
                              void* d_out, int out_size, void* d_ws, size_t ws_size,
                              hipStream_t stream) {
    const float* x     = (const float*)d_in[0];
    const float* adj   = (const float*)d_in[1];
    const float* W     = (const float*)d_in[2];
    // d_in[3] = a_origin: dead (softmax shift invariance over j)
    const float* a_dst = (const float*)d_in[4];
    float* out = (float*)d_out;

    char* ws = (char*)d_ws;
    __bf16* mx = (__bf16*)ws;                     // 4 MB    [4096][512]
    float*  et = (float*)(ws + 4194304);          // 128 KB  [4096][8]

    k1_gemm<<<dim3(512), dim3(256), 0, stream>>>(x, W, a_dst, mx, et);
    k3_aggr<<<dim3(N_NODES), dim3(256), 0, stream>>>(adj, mx, et, out);
}